// Round 6
// baseline (155.837 us; speedup 1.0000x reference)
//
#include <hip/hip_runtime.h>
#include <math.h>

constexpr int BDIM  = 256;
constexpr int Bsz   = 16, Asz = 3, Hsz = 80, Wsz = 80;
constexpr int Csz   = 84;                 // 4 + 80
constexpr int HWsz  = Hsz * Wsz;          // 6400
constexpr int BAsz  = Bsz * Asz;          // 48
constexpr int TOTAL = BAsz * HWsz;        // 307200
constexpr int NTGT  = 64;
constexpr int NCOMBO = BAsz * NTGT;       // 3072
constexpr int GITER = 8;                  // ch4 loads per thread (MLP)
constexpr int GBLK  = TOTAL / (BDIM * GITER);  // 150 gather blocks
constexpr int TBLK  = BAsz;               // 48 target blocks (one per (b,a))
constexpr int NBLK  = GBLK + TBLK;        // 198
constexpr int PAD   = 32;                 // 128 B per block slot: no cross-XCD
                                          // partial-line writeback sharing
static_assert(GBLK * BDIM * GITER == TOTAL, "exact cover");

// fast softplus: logaddexp(x,0) via hw v_exp/v_log; |err| ~1e-6, threshold 6.4e-2
__device__ __forceinline__ float softplus_fast(float x) {
    return fmaxf(x, 0.f) + __logf(1.f + __expf(-fabsf(x)));
}

__global__ __launch_bounds__(BDIM)
void yolo_fused(const float* __restrict__ pred,
                const float* __restrict__ targets,
                float* __restrict__ ws_part,      // [NBLK*PAD]
                unsigned int* __restrict__ counter,
                float* __restrict__ out) {
    float* sp_part  = ws_part;             // [GBLK*PAD], slot wid of each block
    float* tgt_part = ws_part + GBLK * PAD;// [TBLK*PAD], {cls,loc,obj,spt}
    int lane = threadIdx.x & 63, wid = threadIdx.x >> 6;
    __shared__ float smem[NTGT * 5];
    __shared__ float rsm[4][5];
    __shared__ bool  amLast;

    if (blockIdx.x < GBLK) {
        // ---- no-obj gather: 8 scattered line loads back-to-back per thread ----
        int base = blockIdx.x * (BDIM * GITER) + threadIdx.x;
        float v[GITER];
        #pragma unroll
        for (int k = 0; k < GITER; ++k)
            v[k] = pred[(size_t)(base + k * BDIM) * Csz + 4];
        float sp = 0.f;
        #pragma unroll
        for (int k = 0; k < GITER; ++k) sp += softplus_fast(v[k]);
        #pragma unroll
        for (int o = 32; o > 0; o >>= 1) sp += __shfl_down(sp, o, 64);
        if (lane == 0) sp_part[blockIdx.x * PAD + wid] = sp;
    } else {
        // ---- target path: block = one (b,a); wave = 16 targets ----
        int ba = blockIdx.x - GBLK;
        for (int i = threadIdx.x; i < NTGT * 5; i += BDIM) smem[i] = targets[i];
        __syncthreads();

        const float* __restrict__ pb = pred + (size_t)ba * HWsz * Csz;
        float cls = 0.f, locv = 0.f, obj = 0.f, spt = 0.f;

        #pragma unroll 4
        for (int k = 0; k < NTGT / 4; ++k) {
            int t = wid * (NTGT / 4) + k;
            const float* tg = &smem[t * 5];
            float cid_f = tg[0];
            int gx = min(max((int)floorf(tg[1] * (float)Wsz), 0), Wsz - 1);
            int gy = min(max((int)floorf(tg[2] * (float)Hsz), 0), Hsz - 1);
            int cell = gy * Wsz + gx;
            const float* p = pb + (size_t)cell * Csz;
            int cid4 = 4 + (int)cid_f;

            float v0 = p[lane];                    // channels 0..63 across lanes
            if (lane < 4) {
                float d = v0 - tg[1 + lane];       // box = targets[:,1:5]
                locv += d * d;
            } else {
                cls += softplus_fast(v0);          // channels 4..63
            }
            if (lane == 4) {                       // channel 4 = objectness
                obj += softplus_fast(-v0);
                spt += softplus_fast(v0);
            }
            if (lane == cid4) cls -= v0;           // onehot subtract (cid<=59)
            if (lane < 20) {
                float v1 = p[64 + lane];           // channels 64..83
                cls += softplus_fast(v1);
                if (lane + 64 == cid4) cls -= v1;  // onehot subtract (cid>=60)
            }
        }

        float vals[4] = {cls, locv, obj, spt};
        #pragma unroll
        for (int q = 0; q < 4; ++q) {
            float v = vals[q];
            #pragma unroll
            for (int o = 32; o > 0; o >>= 1) v += __shfl_down(v, o, 64);
            vals[q] = v;
        }
        if (lane == 0) {
            #pragma unroll
            for (int q = 0; q < 4; ++q) rsm[wid][q] = vals[q];
        }
        __syncthreads();
        if (threadIdx.x == 0) {
            #pragma unroll
            for (int q = 0; q < 4; ++q)
                tgt_part[ba * PAD + q] =
                    rsm[0][q] + rsm[1][q] + rsm[2][q] + rsm[3][q];
        }
    }

    // ---- last-block-done completion (rocPRIM DeviceReduce idiom) ----
    __syncthreads();                  // partial stores program-ordered in block
    if (threadIdx.x == 0) {
        __threadfence();              // agent-scope release: wb this XCD's L2
        unsigned old = atomicAdd(counter, 1u);
        amLast = (old == (unsigned)(NBLK - 1));
    }
    __syncthreads();
    if (!amLast) return;

    __threadfence();                  // acquire: invalidate stale L1/L2 lines
    float s[5] = {0.f, 0.f, 0.f, 0.f, 0.f};   // {sp_all, cls, loc, obj, spt}
    for (int i = threadIdx.x; i < GBLK * 4; i += BDIM)
        s[0] += sp_part[(i >> 2) * PAD + (i & 3)];
    if (threadIdx.x < TBLK) {
        s[1] = tgt_part[threadIdx.x * PAD + 0];
        s[2] = tgt_part[threadIdx.x * PAD + 1];
        s[3] = tgt_part[threadIdx.x * PAD + 2];
        s[4] = tgt_part[threadIdx.x * PAD + 3];
    }
    #pragma unroll
    for (int q = 0; q < 5; ++q) {
        float v = s[q];
        #pragma unroll
        for (int o = 32; o > 0; o >>= 1) v += __shfl_down(v, o, 64);
        s[q] = v;
    }
    __syncthreads();                  // rsm reuse (target-path values dead now)
    if (lane == 0) {
        #pragma unroll
        for (int q = 0; q < 5; ++q) rsm[wid][q] = s[q];
    }
    __syncthreads();
    if (threadIdx.x == 0) {
        float sp_all = rsm[0][0] + rsm[1][0] + rsm[2][0] + rsm[3][0];
        float cls    = rsm[0][1] + rsm[1][1] + rsm[2][1] + rsm[3][1];
        float loc    = rsm[0][2] + rsm[1][2] + rsm[2][2] + rsm[3][2];
        float obj    = rsm[0][3] + rsm[1][3] + rsm[2][3] + rsm[3][3];
        float spt    = rsm[0][4] + rsm[1][4] + rsm[2][4] + rsm[3][4];
        float loc_loss = loc / (float)(NCOMBO * 4);                      // 12288
        float cls_loss = cls / (float)(NCOMBO * 80);                     // 245760
        float obj_loss = obj / (float)NCOMBO;                            // 3072
        float noobj    = (sp_all - spt) / (float)(BAsz * (HWsz - NTGT)); // 304128
        out[0] = loc_loss + cls_loss + obj_loss + 0.5f * noobj;
    }
}

extern "C" void kernel_launch(void* const* d_in, const int* in_sizes, int n_in,
                              void* d_out, int out_size, void* d_ws, size_t ws_size,
                              hipStream_t stream) {
    const float* pred    = (const float*)d_in[0];
    const float* targets = (const float*)d_in[1];
    float* ws_part = (float*)d_ws;                    // NBLK*PAD floats, rewritten
    unsigned int* counter = (unsigned int*)(ws_part + NBLK * PAD);
    float* out = (float*)d_out;

    hipMemsetAsync(counter, 0, sizeof(unsigned int), stream);
    yolo_fused<<<NBLK, BDIM, 0, stream>>>(pred, targets, ws_part, counter, out);
}

// Round 7
// 149.694 us; speedup vs baseline: 1.0410x; 1.0410x over previous
//
#include <hip/hip_runtime.h>
#include <math.h>

constexpr int BDIM  = 256;
constexpr int Bsz   = 16, Asz = 3, Hsz = 80, Wsz = 80;
constexpr int Csz   = 84;                 // 4 + 80
constexpr int HWsz  = Hsz * Wsz;          // 6400
constexpr int BAsz  = Bsz * Asz;          // 48
constexpr int TOTAL = BAsz * HWsz;        // 307200
constexpr int NTGT  = 64;
constexpr int NCOMBO = BAsz * NTGT;       // 3072
constexpr int GITER = 8;                  // ch4 loads per thread (MLP)
constexpr int GBLK  = TOTAL / (BDIM * GITER);  // 150 gather blocks
constexpr int TBLK  = BAsz;               // 48 target blocks (one per (b,a))
constexpr int NBLK  = GBLK + TBLK;        // 198
constexpr int NSP   = GBLK * 4;           // per-wave partials: 600
static_assert(GBLK * BDIM * GITER == TOTAL, "exact cover");

// fast softplus: logaddexp(x,0) via hw v_exp/v_log; |err| ~1e-6, threshold 6.4e-2
__device__ __forceinline__ float softplus_fast(float x) {
    return fmaxf(x, 0.f) + __logf(1.f + __expf(-fabsf(x)));
}

__global__ __launch_bounds__(BDIM)
void yolo_main(const float* __restrict__ pred,
               const float* __restrict__ targets,
               float* __restrict__ partial_sp,   // [NSP] per-wave
               float* __restrict__ partial_tgt) { // [TBLK*4] {cls,loc,obj,spt}
    int lane = threadIdx.x & 63, wid = threadIdx.x >> 6;

    if (blockIdx.x < GBLK) {
        // ---- no-obj gather: 8 cells per thread, channel 4 only ----
        // All 8 scattered line loads issued back-to-back (8 outstanding
        // misses/thread), then softplus+reduce. No LDS, no syncthreads,
        // no global atomics (cross-XCD same-line atomics measured 15-19
        // ns/op serialized in rounds 1-2).
        int base = blockIdx.x * (BDIM * GITER) + threadIdx.x;
        float v[GITER];
        #pragma unroll
        for (int k = 0; k < GITER; ++k) {
            v[k] = pred[(size_t)(base + k * BDIM) * Csz + 4];
        }
        float sp = 0.f;
        #pragma unroll
        for (int k = 0; k < GITER; ++k) sp += softplus_fast(v[k]);
        #pragma unroll
        for (int o = 32; o > 0; o >>= 1) sp += __shfl_down(sp, o, 64);
        if (lane == 0) partial_sp[blockIdx.x * 4 + wid] = sp;
        return;
    }

    // ---- target path: block handles one (b,a); wave handles 16 targets ----
    __shared__ float smem[NTGT * 5];
    int ba = blockIdx.x - GBLK;
    for (int i = threadIdx.x; i < NTGT * 5; i += BDIM) smem[i] = targets[i];
    __syncthreads();

    const float* __restrict__ pb = pred + (size_t)ba * HWsz * Csz;
    float cls = 0.f, locv = 0.f, obj = 0.f, spt = 0.f;

    #pragma unroll 4
    for (int k = 0; k < NTGT / 4; ++k) {
        int t = wid * (NTGT / 4) + k;
        const float* tg = &smem[t * 5];
        float cid_f = tg[0];
        int gx = min(max((int)floorf(tg[1] * (float)Wsz), 0), Wsz - 1);
        int gy = min(max((int)floorf(tg[2] * (float)Hsz), 0), Hsz - 1);
        int cell = gy * Wsz + gx;
        const float* p = pb + (size_t)cell * Csz;
        int cid4 = 4 + (int)cid_f;

        float v0 = p[lane];                    // channels 0..63 across lanes
        if (lane < 4) {
            float d = v0 - tg[1 + lane];       // box = targets[:,1:5]
            locv += d * d;
        } else {
            cls += softplus_fast(v0);          // channels 4..63
        }
        if (lane == 4) {                       // channel 4 = objectness
            obj += softplus_fast(-v0);
            spt += softplus_fast(v0);
        }
        if (lane == cid4) cls -= v0;           // onehot subtract (cid<=59)
        if (lane < 20) {
            float v1 = p[64 + lane];           // channels 64..83
            cls += softplus_fast(v1);
            if (lane + 64 == cid4) cls -= v1;  // onehot subtract (cid>=60)
        }
    }

    float vals[4] = {cls, locv, obj, spt};
    #pragma unroll
    for (int q = 0; q < 4; ++q) {
        float v = vals[q];
        #pragma unroll
        for (int o = 32; o > 0; o >>= 1) v += __shfl_down(v, o, 64);
        vals[q] = v;
    }
    __shared__ float rsm[4][4];
    if (lane == 0) {
        #pragma unroll
        for (int q = 0; q < 4; ++q) rsm[wid][q] = vals[q];
    }
    __syncthreads();
    if (threadIdx.x == 0) {
        #pragma unroll
        for (int q = 0; q < 4; ++q)
            partial_tgt[ba * 4 + q] = rsm[0][q] + rsm[1][q] + rsm[2][q] + rsm[3][q];
    }
}

__global__ __launch_bounds__(BDIM)
void yolo_final(const float* __restrict__ partial_sp,
                const float* __restrict__ partial_tgt,
                float* __restrict__ out) {
    int lane = threadIdx.x & 63, wid = threadIdx.x >> 6;
    float s[5] = {0.f, 0.f, 0.f, 0.f, 0.f};    // {sp_all, cls, loc, obj, spt}
    for (int i = threadIdx.x; i < NSP; i += BDIM) s[0] += partial_sp[i];
    if (threadIdx.x < TBLK) {
        s[1] = partial_tgt[threadIdx.x * 4 + 0];
        s[2] = partial_tgt[threadIdx.x * 4 + 1];
        s[3] = partial_tgt[threadIdx.x * 4 + 2];
        s[4] = partial_tgt[threadIdx.x * 4 + 3];
    }
    #pragma unroll
    for (int q = 0; q < 5; ++q) {
        float v = s[q];
        #pragma unroll
        for (int o = 32; o > 0; o >>= 1) v += __shfl_down(v, o, 64);
        s[q] = v;
    }
    __shared__ float sm[4][5];
    if (lane == 0) {
        #pragma unroll
        for (int q = 0; q < 5; ++q) sm[wid][q] = s[q];
    }
    __syncthreads();
    if (threadIdx.x == 0) {
        float sp_all = sm[0][0] + sm[1][0] + sm[2][0] + sm[3][0];
        float cls    = sm[0][1] + sm[1][1] + sm[2][1] + sm[3][1];
        float loc    = sm[0][2] + sm[1][2] + sm[2][2] + sm[3][2];
        float obj    = sm[0][3] + sm[1][3] + sm[2][3] + sm[3][3];
        float spt    = sm[0][4] + sm[1][4] + sm[2][4] + sm[3][4];
        float loc_loss = loc / (float)(NCOMBO * 4);                      // 12288
        float cls_loss = cls / (float)(NCOMBO * 80);                     // 245760
        float obj_loss = obj / (float)NCOMBO;                            // 3072
        float noobj    = (sp_all - spt) / (float)(BAsz * (HWsz - NTGT)); // 304128
        out[0] = loc_loss + cls_loss + obj_loss + 0.5f * noobj;
    }
}

extern "C" void kernel_launch(void* const* d_in, const int* in_sizes, int n_in,
                              void* d_out, int out_size, void* d_ws, size_t ws_size,
                              hipStream_t stream) {
    const float* pred    = (const float*)d_in[0];
    const float* targets = (const float*)d_in[1];
    float* partial_sp  = (float*)d_ws;               // 600 floats, fully rewritten
    float* partial_tgt = partial_sp + NSP;           // 192 floats, fully rewritten
    float* out = (float*)d_out;

    yolo_main<<<NBLK, BDIM, 0, stream>>>(pred, targets, partial_sp, partial_tgt);
    yolo_final<<<1, BDIM, 0, stream>>>(partial_sp, partial_tgt, out);
}